// Round 12
// baseline (89.811 us; speedup 1.0000x reference)
//
#include <hip/hip_runtime.h>

#define B_   16
#define T_   2500
#define X_   512
#define XT   32
#define SEGS 5
#define SEGR 512
#define NSX  (X_ / XT)            // 16
#define NBLK (B_ * SEGS * NSX)    // 1280 -> 5 blocks/CU
#define RING 18

typedef __attribute__((ext_vector_type(4))) float f32x4;

// lgkm-only barrier (verified r9): LDS producer->consumer visibility without
// draining vmcnt, so prefetched global loads stay in flight across it.
__device__ __forceinline__ void barrier_lgkm() {
    asm volatile("s_waitcnt lgkmcnt(0)\n\ts_barrier" ::: "memory");
}

// Round-12 = round-11 skeleton (fp8 ring, banded fp8 MFMA x/t-conv, DPP 4x4
// transpose ring writes, static roles + role mixing, 1-period load prefetch,
// XCD swizzle, lgkm barriers, consumer pre-gather) with:
//  - GRID 1024 -> 1280 blocks (SEGS=5, SEGR=512): occupancy was GRID-limited
//    at 4 blocks/CU; 1280 = 5 blocks/CU (the r10 "more-LDS-headroom" attempt
//    could never help at 1024 blocks).
//  - producer-private-rows xconv: fragment n = (row-in-own-8 | col-half):
//    B read = PB[f][8*p01+(ln16&7)][1+2*(ln16>>3)+g]; ring col 16*(ln16>>3)+
//    4g+cidx; slot gb+16+p01. Each producer wave reads only PB rows it wrote
//    itself -> single PB (no ping-pong), LDS 39.4 -> 28.6 KB -> 5 blocks fit.
//  - RING back to 18 (lag-1), ring cols packed 34 -> 32.
__global__ __launch_bounds__(256, 5) void coh12(const float* __restrict__ xg,
                                                const float* __restrict__ yg,
                                                float* __restrict__ partial)
{
    __shared__ float ktn[104];
    __shared__ float kxn[12];
    __shared__ float norm2[2];
    __shared__ unsigned long long XS[RING][5][32];  // 23040 B fp8 ring: byte rs of [slot][f][col] = row-slot
    __shared__ unsigned long long PB[5][16][8];     //  5120 B fp8 products; byte j of row = staged col j
    __shared__ float wred[4];

    const int tid  = threadIdx.x;
    const int lane = tid & 63;
    const int w    = tid >> 6;
    const int g    = lane >> 4;
    const int ln16 = lane & 15;
    const int p01  = w & 1;

    // ---- XCD-aware bijective block swizzle (1280 blocks, 8 XCDs) ----
    const int bid = blockIdx.x;
    const int wid = (bid & 7) * (NBLK / 8) + (bid >> 3);
    const int xt  = wid & 15;
    const int hi5 = wid >> 4;          // 0..79
    const int seg = hi5 % SEGS;
    const int b   = hi5 / SEGS;

    const int pair = ((w >> 1) ^ wid) & 1;   // role-mixed across co-resident blocks

    const int x0    = xt * XT;
    const int t0    = seg * SEGR;
    const int t_end = min(t0 + SEGR, T_);
    const int nm    = (t_end - t0 + 15) >> 4;
    const int pmax  = nm + 8;

    // ---- normalized Gaussian tables ----
    if (tid < 104) ktn[tid] = 0.0f;
    if (tid < 12)  kxn[tid] = 0.0f;
    __syncthreads();
    if (tid < 101) { float d = (float)(tid - 50); ktn[tid] = expf(-d * d / (2.0f * 21.0f * 21.0f)); }
    if (tid < 11)  { float d = (float)(tid - 5);  kxn[tid] = expf(-d * d / (2.0f * 11.0f * 11.0f)); }
    __syncthreads();
    if (tid == 0) {
        float s = 0.f; for (int i = 0; i < 101; ++i) s += ktn[i]; norm2[0] = 1.0f / s;
        s = 0.f;       for (int i = 0; i < 11;  ++i) s += kxn[i]; norm2[1] = 1.0f / s;
    }
    __syncthreads();
    if (tid < 101) ktn[tid] *= norm2[0];
    if (tid < 11)  kxn[tid] *= norm2[1];
    __syncthreads();

    const float* xb = xg + (size_t)b * T_ * X_;
    const float* yb = yg + (size_t)b * T_ * X_;

    float local = 0.f;

    if (pair == 0) {
        // ===================== producer loop =====================
        long a_x;
        {
            float vv[8];
#pragma unroll
            for (int sl = 0; sl < 8; ++sl) {
                int idx = 8 * g + sl - ln16 - 3;
                vv[sl] = (idx >= 0 && idx <= 10) ? kxn[idx] * 16.0f : 0.0f;
            }
            int lo = __builtin_amdgcn_cvt_pk_fp8_f32(vv[0], vv[1], 0, false);
            lo     = __builtin_amdgcn_cvt_pk_fp8_f32(vv[2], vv[3], lo, true);
            int hi = __builtin_amdgcn_cvt_pk_fp8_f32(vv[4], vv[5], 0, false);
            hi     = __builtin_amdgcn_cvt_pk_fp8_f32(vv[6], vv[7], hi, true);
            a_x = (long)(((unsigned long long)(unsigned)hi << 32) | (unsigned)lo);
        }
        // DPP 4x4 byte-transpose constants (verified r5-r11)
        const uint sel1  = (ln16 & 1) ? 0x07030602u : 0x01050004u;
        const uint sel2  = (ln16 & 2) ? 0x07060302u : 0x01000504u;
        const int  cidx  = ((ln16 & 1) << 1) | ((ln16 >> 1) & 1);
        const int  abyte = (ln16 & 4);
        const int  hh    = ln16 >> 3;            // col-half (new n-mapping)
        const int  prow  = 8 * p01 + (ln16 & 7); // own PB row for xconv read

        const int  gcol  = x0 - 16 + 4 * ln16;
        const bool colOK = (gcol >= 0) && (gcol < X_);
        const float* xpl = xb + gcol;
        const float* ypl = yb + gcol;
        const float4 z4  = make_float4(0.f, 0.f, 0.f, 0.f);

        float4 xv[2], yv[2];
        auto issue_loads = [&](int c) {
            const int rowlo = t0 - 56 + 16 * c;
            if (rowlo >= 0 && rowlo + 15 < T_) {          // fast: rows all in-bounds
#pragma unroll
                for (int s = 0; s < 2; ++s) {
                    int grow = rowlo + 8 * p01 + 4 * s + g;
                    xv[s] = colOK ? *(const float4*)(xpl + (size_t)grow * X_) : z4;
                    yv[s] = colOK ? *(const float4*)(ypl + (size_t)grow * X_) : z4;
                }
            } else {                                       // guarded (seg edges only)
#pragma unroll
                for (int s = 0; s < 2; ++s) {
                    int grow = rowlo + 8 * p01 + 4 * s + g;
                    bool ok = colOK && (grow >= 0) && (grow < T_);
                    xv[s] = ok ? *(const float4*)(xpl + (size_t)grow * X_) : z4;
                    yv[s] = ok ? *(const float4*)(ypl + (size_t)grow * X_) : z4;
                }
            }
        };
        issue_loads(0);   // prologue

        int gb = 0;       // (2*it) % 18
        for (int it = 0; it <= pmax; ++it) {
            // ---- xconv-MFMA of chunk it-1 -> ring slot gb+16+p01 (own rows) ----
            if (it >= 1 && it <= nm + 7) {
                int u0 = gb + 16; if (u0 >= RING) u0 -= RING;   // even, <= 16
                const int uu = u0 + p01;                         // own row-group slot
#pragma unroll
                for (int f = 0; f < 5; ++f) {
                    long bfrag = (long)PB[f][prow][1 + 2 * hh + g];
                    f32x4 z; z[0] = 0.f; z[1] = 0.f; z[2] = 0.f; z[3] = 0.f;
                    f32x4 d = __builtin_amdgcn_mfma_f32_16x16x32_fp8_fp8(a_x, bfrag, z, 0, 0, 0);
                    int pk = __builtin_amdgcn_cvt_pk_fp8_f32(d[0], d[1], 0, false);
                    pk     = __builtin_amdgcn_cvt_pk_fp8_f32(d[2], d[3], pk, true);
                    uint pkc   = (uint)pk;
                    uint part1 = (uint)__builtin_amdgcn_update_dpp(0, (int)pkc, 177, 0xF, 0xF, true);
                    uint s1v   = __builtin_amdgcn_perm(pkc, part1, sel1);
                    uint part2 = (uint)__builtin_amdgcn_update_dpp(0, (int)s1v, 78, 0xF, 0xF, true);
                    uint Tt    = __builtin_amdgcn_perm(s1v, part2, sel2);
                    *(uint*)((uchar*)&XS[uu][f][16 * hh + 4 * g + cidx] + abyte) = Tt;
                }
            }
            // ---- products of chunk it -> own PB rows (consume prefetched loads) ----
            if (it <= nm + 6) {
#pragma unroll
                for (int s = 0; s < 2; ++s) {
                    int rrs = 8 * p01 + 4 * s + g;
                    float4 X = xv[s], Y = yv[s];
                    int q0 = __builtin_amdgcn_cvt_pk_fp8_f32(X.x, X.y, 0, false);
                    q0     = __builtin_amdgcn_cvt_pk_fp8_f32(X.z, X.w, q0, true);
                    int q1 = __builtin_amdgcn_cvt_pk_fp8_f32(Y.x, Y.y, 0, false);
                    q1     = __builtin_amdgcn_cvt_pk_fp8_f32(Y.z, Y.w, q1, true);
                    int q2 = __builtin_amdgcn_cvt_pk_fp8_f32(X.x * X.x, X.y * X.y, 0, false);
                    q2     = __builtin_amdgcn_cvt_pk_fp8_f32(X.z * X.z, X.w * X.w, q2, true);
                    int q3 = __builtin_amdgcn_cvt_pk_fp8_f32(Y.x * Y.x, Y.y * Y.y, 0, false);
                    q3     = __builtin_amdgcn_cvt_pk_fp8_f32(Y.z * Y.z, Y.w * Y.w, q3, true);
                    int q4 = __builtin_amdgcn_cvt_pk_fp8_f32(X.x * Y.x, X.y * Y.y, 0, false);
                    q4     = __builtin_amdgcn_cvt_pk_fp8_f32(X.z * Y.z, X.w * Y.w, q4, true);
                    *(uint*)((uchar*)&PB[0][rrs][0] + 4 * ln16) = (uint)q0;
                    *(uint*)((uchar*)&PB[1][rrs][0] + 4 * ln16) = (uint)q1;
                    *(uint*)((uchar*)&PB[2][rrs][0] + 4 * ln16) = (uint)q2;
                    *(uint*)((uchar*)&PB[3][rrs][0] + 4 * ln16) = (uint)q3;
                    *(uint*)((uchar*)&PB[4][rrs][0] + 4 * ln16) = (uint)q4;
                }
            }
            // ---- issue loads for chunk it+1 (in flight across the raw barrier) ----
            if (it + 1 <= nm + 6) issue_loads(it + 1);
            barrier_lgkm();
            gb += 2; if (gb >= RING) gb -= RING;
        }
    } else {
        // ===================== consumer loop =====================
        long a_t[4];
#pragma unroll
        for (int c = 0; c < 4; ++c) {
            float vv[8];
#pragma unroll
            for (int sl = 0; sl < 8; ++sl) {
                int idx = 32 * c + 8 * g + sl - ln16 - 6;
                vv[sl] = (idx >= 0 && idx <= 100) ? ktn[idx] * 16.0f : 0.0f;
            }
            int lo = __builtin_amdgcn_cvt_pk_fp8_f32(vv[0], vv[1], 0, false);
            lo     = __builtin_amdgcn_cvt_pk_fp8_f32(vv[2], vv[3], lo, true);
            int hi = __builtin_amdgcn_cvt_pk_fp8_f32(vv[4], vv[5], 0, false);
            hi     = __builtin_amdgcn_cvt_pk_fp8_f32(vv[6], vv[7], hi, true);
            a_t[c] = (long)(((unsigned long long)(unsigned)hi << 32) | (unsigned)lo);
        }

        int gb = 0;       // (2*it) % 18; consumer strip m = it-9 starts at slot gb
        for (int it = 0; it <= pmax; ++it) {
            if (it >= 9) {
                const int m = it - 9;
                // pre-gather all 20 fragments (static indices), one lgkm wait
                long bf0[5], bf1[5], bf2[5], bf3[5];
                {
                    int u0 = gb + g;      if (u0 >= RING) u0 -= RING;
                    int u1 = gb + 4 + g;  if (u1 >= RING) u1 -= RING;
                    int u2 = gb + 8 + g;  if (u2 >= RING) u2 -= RING;
                    int u3 = gb + 12 + g; if (u3 >= RING) u3 -= RING;
                    const int nn = 16 * p01 + ln16;
#pragma unroll
                    for (int f = 0; f < 5; ++f) bf0[f] = (long)XS[u0][f][nn];
#pragma unroll
                    for (int f = 0; f < 5; ++f) bf1[f] = (long)XS[u1][f][nn];
#pragma unroll
                    for (int f = 0; f < 5; ++f) bf2[f] = (long)XS[u2][f][nn];
#pragma unroll
                    for (int f = 0; f < 5; ++f) bf3[f] = (long)XS[u3][f][nn];
                }
                f32x4 acc[5];
#pragma unroll
                for (int f = 0; f < 5; ++f) { acc[f][0] = 0.f; acc[f][1] = 0.f; acc[f][2] = 0.f; acc[f][3] = 0.f; }
#pragma unroll
                for (int f = 0; f < 5; ++f) acc[f] = __builtin_amdgcn_mfma_f32_16x16x32_fp8_fp8(a_t[0], bf0[f], acc[f], 0, 0, 0);
#pragma unroll
                for (int f = 0; f < 5; ++f) acc[f] = __builtin_amdgcn_mfma_f32_16x16x32_fp8_fp8(a_t[1], bf1[f], acc[f], 0, 0, 0);
#pragma unroll
                for (int f = 0; f < 5; ++f) acc[f] = __builtin_amdgcn_mfma_f32_16x16x32_fp8_fp8(a_t[2], bf2[f], acc[f], 0, 0, 0);
#pragma unroll
                for (int f = 0; f < 5; ++f) acc[f] = __builtin_amdgcn_mfma_f32_16x16x32_fp8_fp8(a_t[3], bf3[f], acc[f], 0, 0, 0);

                const float s_ = 1.0f / 256.0f;   // undo kt(16)*kx(16) scaling
                if (16 * m + 15 < t_end - t0) {   // fast: whole strip valid
#pragma unroll
                    for (int r = 0; r < 4; ++r) {
                        float a0 = acc[0][r], a1 = acc[1][r];
                        float sa0 = a0 * s_, sa1 = a1 * s_;
                        float cov = fmaf(-sa0, a1, acc[4][r]);
                        float vx  = fmaf(-sa0, a0, acc[2][r]);
                        float vy  = fmaf(-sa1, a1, acc[3][r]);
                        local += 1.0f - cov * rsqrtf(fmaf(vx, vy, 6.5536e-5f));
                    }
                } else {                           // guarded (last strips of seg 4)
#pragma unroll
                    for (int r = 0; r < 4; ++r) {
                        int t = t0 + 16 * m + 4 * g + r;
                        if (t < t_end) {
                            float a0 = acc[0][r], a1 = acc[1][r];
                            float sa0 = a0 * s_, sa1 = a1 * s_;
                            float cov = fmaf(-sa0, a1, acc[4][r]);
                            float vx  = fmaf(-sa0, a0, acc[2][r]);
                            float vy  = fmaf(-sa1, a1, acc[3][r]);
                            local += 1.0f - cov * rsqrtf(fmaf(vx, vy, 6.5536e-5f));
                        }
                    }
                }
            }
            barrier_lgkm();
            gb += 2; if (gb >= RING) gb -= RING;
        }
    }

    // ---- block reduction ----
#pragma unroll
    for (int off = 32; off >= 1; off >>= 1) local += __shfl_down(local, off);
    if ((tid & 63) == 0) wred[tid >> 6] = local;
    __syncthreads();
    if (tid == 0)
        partial[wid] = wred[0] + wred[1] + wred[2] + wred[3];
}

__global__ __launch_bounds__(256) void coh_reduce(const float* __restrict__ partial,
                                                  float* __restrict__ out) {
    __shared__ float wred[4];
    const int tid = threadIdx.x;
    float s = 0.0f;
    for (int i = tid; i < NBLK; i += 256) s += partial[i];
#pragma unroll
    for (int off = 32; off >= 1; off >>= 1) s += __shfl_down(s, off);
    if ((tid & 63) == 0) wred[tid >> 6] = s;
    __syncthreads();
    if (tid == 0)
        out[0] = (wred[0] + wred[1] + wred[2] + wred[3]) *
                 (1.0f / ((float)B_ * (float)T_ * (float)X_));
}

extern "C" void kernel_launch(void* const* d_in, const int* in_sizes, int n_in,
                              void* d_out, int out_size, void* d_ws, size_t ws_size,
                              hipStream_t stream) {
    const float* x = (const float*)d_in[0];
    const float* y = (const float*)d_in[1];
    float* out = (float*)d_out;
    float* partial = (float*)d_ws;   // NBLK floats = 5 KB

    coh12<<<dim3(NBLK), 256, 0, stream>>>(x, y, partial);
    coh_reduce<<<1, 256, 0, stream>>>(partial, out);
}